// Round 8
// baseline (347.178 us; speedup 1.0000x reference)
//
#include <hip/hip_runtime.h>

// SGC_LL: B=64, M=512, FIN=OUT=128, K=2. Outputs: out | res_L | W (fp32, concat).
//
// factor == 1 STRUCTURALLY (|L_ij|<=1 => ||L||_F<=512 => avg<=1/512 => min(1/(avg+1e-6),1)=1).
//
// W is written ONCE and never re-read: gram is only 4.3 GF so k_fuse recomputes
// its G strip via MFMA (bitwise-identical to k_dis's) instead of reading 67 MB.
//
//  K1 k_xw  : xw = x@M_L -> xwb (bf16), sq; xTb = x^T (bf16)      [fp32 LDS GEMM]
//  K2 k_dis : G = xwb@xwb^T (MFMA) -> rowsum(exp(-dist)) -> dis   [no W store]
//  K3 k_fuse: per 128-j chunk: recompute G -> W (out2) + resL (out1) + L_all bf16
//             -> LDS transpose -> y += L_all@x (MFMA vs xTb); then projection:
//             out = leaky(interleave(x,y)@weight + bias) (out0)
//
// Fragment maps (gfx950, m89): A: row=l&15, k=(l>>4)*8+j; B: col=l&15 same k;
// D: row=(l>>4)*4+reg, col=l&15.

#define BB 64
#define MM 512
#define FINC 128
#define OUTC 128

typedef short bf16x8 __attribute__((ext_vector_type(8)));
typedef float f32x4 __attribute__((ext_vector_type(4)));

__device__ __forceinline__ float leaky_(float v) { return v >= 0.0f ? v : 0.01f * v; }
__device__ __forceinline__ unsigned short f2bf(float f) {
    unsigned int u = __float_as_uint(f);
    return (unsigned short)((u + 0x7FFF + ((u >> 16) & 1)) >> 16);
}

// ---------------------------------------------------------------- K1: xw & sq & xT
__global__ __launch_bounds__(256) void k_xw(const float* __restrict__ x,
                                            const float* __restrict__ ml,
                                            unsigned short* __restrict__ xwb,
                                            float* __restrict__ sq,
                                            unsigned short* __restrict__ xTb) {
    const int b = blockIdx.y, i0 = blockIdx.x * 64;
    const int tid = threadIdx.x, ty4 = (tid >> 4) * 4, tx4 = (tid & 15) * 4;
    __shared__ float a_t[64][129];
    __shared__ float b_t[64][129];
    __shared__ float red[64][17];

    const float* xb = x + ((size_t)b * MM + i0) * FINC;
#pragma unroll
    for (int q = 0; q < 8; ++q) {
        int idx4 = tid + q * 256;
        int r = idx4 >> 5, k4 = (idx4 & 31) * 4;
        float4 v = *(const float4*)(xb + r * FINC + k4);
        a_t[r][k4 + 0] = v.x; a_t[r][k4 + 1] = v.y;
        a_t[r][k4 + 2] = v.z; a_t[r][k4 + 3] = v.w;
    }

    float acc[4][8];
#pragma unroll
    for (int m = 0; m < 4; ++m)
#pragma unroll
        for (int n = 0; n < 8; ++n) acc[m][n] = 0.0f;

    for (int kc = 0; kc < 2; ++kc) {
        __syncthreads();
#pragma unroll
        for (int q = 0; q < 8; ++q) {
            int idx4 = tid + q * 256;
            int kk = idx4 >> 5, c4 = (idx4 & 31) * 4;
            float4 v = *(const float4*)(ml + (size_t)(kc * 64 + kk) * FINC + c4);
            b_t[kk][c4 + 0] = v.x; b_t[kk][c4 + 1] = v.y;
            b_t[kk][c4 + 2] = v.z; b_t[kk][c4 + 3] = v.w;
        }
        __syncthreads();
#pragma unroll 4
        for (int k = 0; k < 64; ++k) {
            float av[4], bv[8];
#pragma unroll
            for (int m = 0; m < 4; ++m) av[m] = a_t[ty4 + m][kc * 64 + k];
#pragma unroll
            for (int n = 0; n < 4; ++n) { bv[n] = b_t[k][tx4 + n]; bv[4 + n] = b_t[k][64 + tx4 + n]; }
#pragma unroll
            for (int m = 0; m < 4; ++m)
#pragma unroll
                for (int n = 0; n < 8; ++n) acc[m][n] = fmaf(av[m], bv[n], acc[m][n]);
        }
    }

    unsigned short* xwbb = xwb + ((size_t)b * MM + i0) * FINC;
#pragma unroll
    for (int m = 0; m < 4; ++m) {
        ushort4 h0, h1;
        h0.x = f2bf(acc[m][0]); h0.y = f2bf(acc[m][1]); h0.z = f2bf(acc[m][2]); h0.w = f2bf(acc[m][3]);
        h1.x = f2bf(acc[m][4]); h1.y = f2bf(acc[m][5]); h1.z = f2bf(acc[m][6]); h1.w = f2bf(acc[m][7]);
        *(ushort4*)(xwbb + (ty4 + m) * FINC + tx4) = h0;
        *(ushort4*)(xwbb + (ty4 + m) * FINC + 64 + tx4) = h1;
        float p = 0.0f;
#pragma unroll
        for (int n = 0; n < 8; ++n) p = fmaf(acc[m][n], acc[m][n], p);
        red[ty4 + m][tid & 15] = p;
    }
    __syncthreads();
    if (tid < 64) {
        float s = 0.0f;
#pragma unroll
        for (int t = 0; t < 16; ++t) s += red[tid][t];
        sq[b * MM + i0 + tid] = s;
    }
#pragma unroll
    for (int q = 0; q < 16; ++q) {
        int idx = tid + q * 256;
        int c = idx >> 5, j2 = (idx & 31) * 2;
        ushort2 t;
        t.x = f2bf(a_t[j2][c]);
        t.y = f2bf(a_t[j2 + 1][c]);
        *(ushort2*)(xTb + ((size_t)b * FINC + c) * MM + i0 + j2) = t;
    }
}

// ------------------- K2: gram via MFMA -> rowsum -> dis (no W store)
__global__ __launch_bounds__(256) void k_dis(const unsigned short* __restrict__ xwb,
                                             const float* __restrict__ sq,
                                             float* __restrict__ dis) {
    const int b = blockIdx.y, i0 = blockIdx.x * 64;
    const int tid = threadIdx.x;
    const int w = tid >> 6, l = tid & 63, lr = l & 15, lg = l >> 4;
    const unsigned short* xb = xwb + (size_t)b * MM * FINC;
    const int ia = i0 + w * 16 + lr;
    const unsigned short* arow = xb + (size_t)ia * FINC + lg * 8;
    bf16x8 a0 = *(const bf16x8*)(arow + 0);
    bf16x8 a1 = *(const bf16x8*)(arow + 32);
    bf16x8 a2 = *(const bf16x8*)(arow + 64);
    bf16x8 a3 = *(const bf16x8*)(arow + 96);

    const int id0 = i0 + w * 16 + lg * 4;
    const float* sqb = sq + b * MM;
    const float si0 = sqb[id0 + 0], si1 = sqb[id0 + 1], si2 = sqb[id0 + 2], si3 = sqb[id0 + 3];
    float rs0 = 0.f, rs1 = 0.f, rs2 = 0.f, rs3 = 0.f;

    // prefetch-1 on the j-tile stream
    const unsigned short* jr0 = xb + (size_t)lr * FINC + lg * 8;
    bf16x8 c0 = *(const bf16x8*)(jr0 + 0);
    bf16x8 c1 = *(const bf16x8*)(jr0 + 32);
    bf16x8 c2 = *(const bf16x8*)(jr0 + 64);
    bf16x8 c3 = *(const bf16x8*)(jr0 + 96);
    float sjc = sqb[lr];

#pragma unroll
    for (int tl = 0; tl < 32; ++tl) {
        const int nt = (tl < 31) ? tl + 1 : 31;
        const unsigned short* nr = xb + (size_t)(nt * 16 + lr) * FINC + lg * 8;
        bf16x8 n0 = *(const bf16x8*)(nr + 0);
        bf16x8 n1 = *(const bf16x8*)(nr + 32);
        bf16x8 n2 = *(const bf16x8*)(nr + 64);
        bf16x8 n3 = *(const bf16x8*)(nr + 96);
        float sjn = sqb[nt * 16 + lr];

        f32x4 acc = {0.f, 0.f, 0.f, 0.f};
        acc = __builtin_amdgcn_mfma_f32_16x16x32_bf16(a0, c0, acc, 0, 0, 0);
        acc = __builtin_amdgcn_mfma_f32_16x16x32_bf16(a1, c1, acc, 0, 0, 0);
        acc = __builtin_amdgcn_mfma_f32_16x16x32_bf16(a2, c2, acc, 0, 0, 0);
        acc = __builtin_amdgcn_mfma_f32_16x16x32_bf16(a3, c3, acc, 0, 0, 0);

        const int jc = tl * 16 + lr;
        float d2;
        d2 = si0 + sjc - 2.f * acc[0]; if (id0 + 0 == jc) d2 = 0.f;
        rs0 += __expf(-sqrtf(fmaxf(d2, 1e-12f)));
        d2 = si1 + sjc - 2.f * acc[1]; if (id0 + 1 == jc) d2 = 0.f;
        rs1 += __expf(-sqrtf(fmaxf(d2, 1e-12f)));
        d2 = si2 + sjc - 2.f * acc[2]; if (id0 + 2 == jc) d2 = 0.f;
        rs2 += __expf(-sqrtf(fmaxf(d2, 1e-12f)));
        d2 = si3 + sjc - 2.f * acc[3]; if (id0 + 3 == jc) d2 = 0.f;
        rs3 += __expf(-sqrtf(fmaxf(d2, 1e-12f)));

        c0 = n0; c1 = n1; c2 = n2; c3 = n3; sjc = sjn;
    }
#pragma unroll
    for (int msk = 1; msk < 16; msk <<= 1) {
        rs0 += __shfl_xor(rs0, msk);
        rs1 += __shfl_xor(rs1, msk);
        rs2 += __shfl_xor(rs2, msk);
        rs3 += __shfl_xor(rs3, msk);
    }
    if (lr == 0) {
        dis[b * MM + id0 + 0] = 1.0f / sqrtf(rs0 + 1e-7f);
        dis[b * MM + id0 + 1] = 1.0f / sqrtf(rs1 + 1e-7f);
        dis[b * MM + id0 + 2] = 1.0f / sqrtf(rs2 + 1e-7f);
        dis[b * MM + id0 + 3] = 1.0f / sqrtf(rs3 + 1e-7f);
    }
}

// ---- K3: recompute G -> W(out2)+resL(out1)+L_all; y=(L_all)@x; projection -> out0
__global__ __launch_bounds__(256) void k_fuse(const unsigned short* __restrict__ xwb,
                                              const unsigned short* __restrict__ xTb,
                                              const float* __restrict__ sq,
                                              const float* __restrict__ dis,
                                              const float* __restrict__ La,
                                              const float* __restrict__ x,
                                              const float* __restrict__ weight,
                                              const float* __restrict__ bias,
                                              float* __restrict__ Wout,
                                              float* __restrict__ resL,
                                              float* __restrict__ out) {
    const int b = blockIdx.y, i0 = blockIdx.x * 64;
    const int tid = threadIdx.x;
    const int w = tid >> 6, l = tid & 63, lr = l & 15, lg = l >> 4;
    const int ia = i0 + w * 16 + lr;          // A-layout row (gram + PV + projection)
    const int id0 = i0 + w * 16 + lg * 4;     // D-layout row base

    const unsigned short* xb = xwb + (size_t)b * MM * FINC;
    const unsigned short* xTm = xTb + (size_t)b * FINC * MM;
    const float* sqb = sq + b * MM;
    const float* disb = dis + b * MM;
    float* Wb = Wout + (size_t)b * MM * MM;
    float* Rb = resL + (size_t)b * MM * MM;
    const float* Lab = La + (size_t)b * MM * MM;

    __shared__ unsigned short LT[64][136];    // L_all tile (later reused for y)

    // own gram A-frags (row ia, K=128)
    const unsigned short* arow = xb + (size_t)ia * FINC + lg * 8;
    bf16x8 a0 = *(const bf16x8*)(arow + 0);
    bf16x8 a1 = *(const bf16x8*)(arow + 32);
    bf16x8 a2 = *(const bf16x8*)(arow + 64);
    bf16x8 a3 = *(const bf16x8*)(arow + 96);

    float si[4], dsi[4];
#pragma unroll
    for (int r = 0; r < 4; ++r) { si[r] = sqb[id0 + r]; dsi[r] = disb[id0 + r]; }

    f32x4 acc[8];
#pragma unroll
    for (int n = 0; n < 8; ++n) acc[n] = (f32x4){0.f, 0.f, 0.f, 0.f};

    for (int ch = 0; ch < 4; ++ch) {          // 128 j per chunk
        const int jbase = ch * 128;
#pragma unroll
        for (int n8 = 0; n8 < 8; ++n8) {      // 8 j-tiles of 16
            const int jc = jbase + n8 * 16 + lr;
            const unsigned short* jrow = xb + (size_t)jc * FINC + lg * 8;
            bf16x8 b0 = *(const bf16x8*)(jrow + 0);
            bf16x8 b1 = *(const bf16x8*)(jrow + 32);
            bf16x8 b2 = *(const bf16x8*)(jrow + 64);
            bf16x8 b3 = *(const bf16x8*)(jrow + 96);
            f32x4 g = {0.f, 0.f, 0.f, 0.f};
            g = __builtin_amdgcn_mfma_f32_16x16x32_bf16(a0, b0, g, 0, 0, 0);
            g = __builtin_amdgcn_mfma_f32_16x16x32_bf16(a1, b1, g, 0, 0, 0);
            g = __builtin_amdgcn_mfma_f32_16x16x32_bf16(a2, b2, g, 0, 0, 0);
            g = __builtin_amdgcn_mfma_f32_16x16x32_bf16(a3, b3, g, 0, 0, 0);
            const float sj = sqb[jc];
            const float dj = disb[jc];
#pragma unroll
            for (int r = 0; r < 4; ++r) {
                const int gi = id0 + r;
                float d2 = si[r] + sj - 2.f * g[r];
                const bool dg = (gi == jc);
                if (dg) d2 = 0.f;
                const float wv = __expf(-sqrtf(fmaxf(d2, 1e-12f)));
                Wb[(size_t)gi * MM + jc] = wv;
                const float Lv = (dg ? 1.0f : 0.0f) - dsi[r] * wv * dj;
                const float rv = leaky_(Lv);   // factor == 1 structurally
                Rb[(size_t)gi * MM + jc] = rv;
                LT[w * 16 + lg * 4 + r][n8 * 16 + lr] = f2bf(rv + Lab[(size_t)gi * MM + jc]);
            }
        }
        __syncthreads();
        // PV for this 128-j chunk: acc[n] += L_all * xT
#pragma unroll
        for (int kidx = 0; kidx < 4; ++kidx) {
            bf16x8 af = *(const bf16x8*)&LT[w * 16 + lr][kidx * 32 + lg * 8];
#pragma unroll
            for (int n = 0; n < 8; ++n) {
                bf16x8 bf = *(const bf16x8*)(xTm + (size_t)(n * 16 + lr) * MM + jbase + kidx * 32 + lg * 8);
                acc[n] = __builtin_amdgcn_mfma_f32_16x16x32_bf16(af, bf, acc[n], 0, 0, 0);
            }
        }
        __syncthreads();
    }

    // ---- y -> LDS (reuse LT; D layout: row = w*16+lg*4+rg, col = n*16+lr)
    const int r0l = w * 16 + lg * 4;
#pragma unroll
    for (int n = 0; n < 8; ++n) {
        const int col = n * 16 + lr;
#pragma unroll
        for (int rg = 0; rg < 4; ++rg)
            LT[r0l + rg][col] = f2bf(acc[n][rg]);
    }
    __syncthreads();

    // ---- projection: out = leaky(interleave(x,y) @ weight + bias)
    const float* xr = x + ((size_t)b * MM + ia) * FINC;
    const int yrow = w * 16 + lr;
    f32x4 acc2[8];
#pragma unroll
    for (int n = 0; n < 8; ++n) acc2[n] = (f32x4){0.f, 0.f, 0.f, 0.f};

#pragma unroll
    for (int chp = 0; chp < 8; ++chp) {
        const int koff = chp * 32 + lg * 8;   // K = 256 interleaved (x,y)
        const int f0 = koff >> 1;             // 4 features
        float4 xv = *(const float4*)(xr + f0);
        ushort4 yv = *(const ushort4*)&LT[yrow][f0];
        bf16x8 af;
        af[0] = (short)f2bf(xv.x); af[1] = (short)yv.x;
        af[2] = (short)f2bf(xv.y); af[3] = (short)yv.y;
        af[4] = (short)f2bf(xv.z); af[5] = (short)yv.z;
        af[6] = (short)f2bf(xv.w); af[7] = (short)yv.w;
#pragma unroll
        for (int n = 0; n < 8; ++n) {
            const int col = n * 16 + lr;
            bf16x8 bf;
#pragma unroll
            for (int j = 0; j < 8; ++j)
                bf[j] = (short)f2bf(weight[(size_t)(koff + j) * OUTC + col]);
            acc2[n] = __builtin_amdgcn_mfma_f32_16x16x32_bf16(af, bf, acc2[n], 0, 0, 0);
        }
    }

    float* ob = out + (size_t)b * MM * OUTC;
#pragma unroll
    for (int n = 0; n < 8; ++n) {
        const int col = n * 16 + lr;
        const float bs = bias[col];
#pragma unroll
        for (int rg = 0; rg < 4; ++rg)
            ob[(size_t)(id0 + rg) * OUTC + col] = leaky_(acc2[n][rg] + bs);
    }
}

// -----------------------------------------------------------------------------
extern "C" void kernel_launch(void* const* d_in, const int* in_sizes, int n_in,
                              void* d_out, int out_size, void* d_ws, size_t ws_size,
                              hipStream_t stream) {
    const float* x      = (const float*)d_in[0];   // [64,512,128]
    const float* La     = (const float*)d_in[1];   // [64,512,512]
    const float* weight = (const float*)d_in[2];   // [256,128]
    const float* bias   = (const float*)d_in[3];   // [128]
    const float* ml     = (const float*)d_in[4];   // [128,128]

    float* out0 = (float*)d_out;                                   // out
    float* out1 = out0 + (size_t)BB * MM * OUTC;                   // res_L
    float* out2 = out1 + (size_t)BB * MM * MM;                     // W

    // ws layout (17,039,360 B):
    //  [0,       8388608)  xwb bf16
    //  [8388608, 16777216) xTb bf16
    //  [16777216,16908288) sq f32
    //  [16908288,17039360) dis f32
    unsigned short* xwb = (unsigned short*)d_ws;
    unsigned short* xTb = xwb + 4194304;
    float* sq  = (float*)((char*)d_ws + 16777216);
    float* dis = sq + 32768;

    dim3 blk(256);
    k_xw   <<<dim3(8, BB), blk, 0, stream>>>(x, ml, xwb, sq, xTb);
    k_dis  <<<dim3(8, BB), blk, 0, stream>>>(xwb, sq, dis);
    k_fuse <<<dim3(8, BB), blk, 0, stream>>>(xwb, xTb, sq, dis, La, x, weight, bias, out2, out1, out0);
}